// Round 1
// baseline (46.927 us; speedup 1.0000x reference)
//
#include <hip/hip_runtime.h>
#include <cstdint>

#define IN_DIM  512
#define OUT_DIM 512
#define BATCH   512
#define KPI     12                 // 11 basis + 1 silu slot per input dim
#define KTOT    (IN_DIM * KPI)     // 6144
#define TILE    64
#define KC      32
#define SPLITK  8
#define KCHUNK  (KTOT / SPLITK)    // 768
#define NSTEP   (KCHUNK / KC)      // 24

typedef __attribute__((ext_vector_type(8))) short bf16x8;
typedef __attribute__((ext_vector_type(4))) float f32x4;

static __device__ __forceinline__ unsigned short f2bf(float f) {
  union { float f; unsigned int u; } v; v.f = f;
  return (unsigned short)((v.u + 0x7FFFu + ((v.u >> 16) & 1u)) >> 16);  // RNE
}

// A[b][i*12 + k] : k=0..10 spline basis of x[b,i], k=11 silu(x[b,i]).  bf16, row-major (K-minor).
__global__ __launch_bounds__(256) void build_A(const float* __restrict__ x,
                                               const float* __restrict__ grid,
                                               unsigned short* __restrict__ A) {
  const int idx = blockIdx.x * 256 + threadIdx.x;      // idx = b*512 + i
  const int i = idx & (IN_DIM - 1);
  const float xv = x[idx];
  float g[15];
#pragma unroll
  for (int t = 0; t < 15; ++t) g[t] = grid[i * 15 + t];
  float B[14];
#pragma unroll
  for (int t = 0; t < 14; ++t) B[t] = (xv >= g[t] && xv < g[t + 1]) ? 1.0f : 0.0f;
#pragma unroll
  for (int j = 1; j <= 3; ++j) {
#pragma unroll
    for (int t = 0; t + j < 14; ++t) {
      const float left  = (xv - g[t]) / (g[t + j] - g[t]);
      const float right = (g[t + j + 1] - xv) / (g[t + j + 1] - g[t + 1]);
      B[t] = left * B[t] + right * B[t + 1];
    }
  }
  const float silu = xv / (1.0f + __expf(-xv));
  unsigned short* dst = A + (size_t)idx * KPI;         // == A[b*6144 + i*12]
  const ushort4 p0 = make_ushort4(f2bf(B[0]), f2bf(B[1]), f2bf(B[2]),  f2bf(B[3]));
  const ushort4 p1 = make_ushort4(f2bf(B[4]), f2bf(B[5]), f2bf(B[6]),  f2bf(B[7]));
  const ushort4 p2 = make_ushort4(f2bf(B[8]), f2bf(B[9]), f2bf(B[10]), f2bf(silu));
  ((ushort4*)dst)[0] = p0; ((ushort4*)dst)[1] = p1; ((ushort4*)dst)[2] = p2;
}

// Wt[o][i*12 + k] = mask*scale_sp*coef[i,o,k] (k<11), mask*scale_base[i,o] (k=11). bf16, K-minor.
__global__ __launch_bounds__(256) void build_W(const float* __restrict__ coef,
                                               const float* __restrict__ sb,
                                               const float* __restrict__ ss,
                                               const float* __restrict__ mask,
                                               unsigned short* __restrict__ Wt) {
  const int idx = blockIdx.x * 256 + threadIdx.x;
  const int o = idx & (OUT_DIM - 1);
  const int i = idx >> 9;
  const int io = i * OUT_DIM + o;
  const float m   = mask[io];
  const float scs = m * ss[io];
  const float scb = m * sb[io];
  const float* cp = coef + (size_t)io * 11;
  float c[11];
#pragma unroll
  for (int k = 0; k < 11; ++k) c[k] = scs * cp[k];
  unsigned short* dst = Wt + (size_t)o * KTOT + i * KPI;
  const ushort4 p0 = make_ushort4(f2bf(c[0]), f2bf(c[1]), f2bf(c[2]),  f2bf(c[3]));
  const ushort4 p1 = make_ushort4(f2bf(c[4]), f2bf(c[5]), f2bf(c[6]),  f2bf(c[7]));
  const ushort4 p2 = make_ushort4(f2bf(c[8]), f2bf(c[9]), f2bf(c[10]), f2bf(scb));
  ((ushort4*)dst)[0] = p0; ((ushort4*)dst)[1] = p1; ((ushort4*)dst)[2] = p2;
}

// out(512x512,f32) += A(512x6144,bf16) @ Wt^T(6144x512,bf16).  64x64 tile, split-K=8, atomic epilogue.
__global__ __launch_bounds__(256) void gemm_kan(const unsigned short* __restrict__ A,
                                                const unsigned short* __restrict__ Wt,
                                                float* __restrict__ out) {
  __shared__ unsigned short lds[2][2][TILE * KC];      // [buf][0=A,1=W][64*32] = 16 KiB
  const int tid  = threadIdx.x;
  const int lane = tid & 63;
  const int wq   = tid >> 6;                           // wave 0..3
  const int r0   = (blockIdx.x & 7) * TILE;
  const int c0   = (blockIdx.x >> 3) * TILE;
  const int kk0  = blockIdx.y * KCHUNK;

  // staging: thread t loads 16B of row (t>>2), k-slot (t&3); LDS dest = wave-uniform base + lane*16
  const unsigned short* ga = A  + (size_t)(r0 + (tid >> 2)) * KTOT + kk0 + (tid & 3) * 8;
  const unsigned short* gw = Wt + (size_t)(c0 + (tid >> 2)) * KTOT + kk0 + (tid & 3) * 8;

  const int qr = (wq >> 1) * 32;                       // wave's 32x32 quadrant
  const int qc = (wq & 1) * 32;

  f32x4 acc00 = {0.f, 0.f, 0.f, 0.f};
  f32x4 acc01 = acc00, acc10 = acc00, acc11 = acc00;

  __builtin_amdgcn_global_load_lds((const __attribute__((address_space(1))) void*)ga,
                                   (__attribute__((address_space(3))) void*)&lds[0][0][wq * 512], 16, 0, 0);
  __builtin_amdgcn_global_load_lds((const __attribute__((address_space(1))) void*)gw,
                                   (__attribute__((address_space(3))) void*)&lds[0][1][wq * 512], 16, 0, 0);
  __syncthreads();

  const int aoff = (lane & 15) * KC + (lane >> 4) * 8; // identical sigma for A-frag and B-frag
  for (int t = 0; t < NSTEP; ++t) {
    const int buf = t & 1;
    if (t + 1 < NSTEP) {
      __builtin_amdgcn_global_load_lds((const __attribute__((address_space(1))) void*)(ga + (t + 1) * KC),
                                       (__attribute__((address_space(3))) void*)&lds[buf ^ 1][0][wq * 512], 16, 0, 0);
      __builtin_amdgcn_global_load_lds((const __attribute__((address_space(1))) void*)(gw + (t + 1) * KC),
                                       (__attribute__((address_space(3))) void*)&lds[buf ^ 1][1][wq * 512], 16, 0, 0);
    }
    const unsigned short* la = &lds[buf][0][0];
    const unsigned short* lw = &lds[buf][1][0];
    const bf16x8 a0 = *(const bf16x8*)&la[(qr     ) * KC + aoff];
    const bf16x8 a1 = *(const bf16x8*)&la[(qr + 16) * KC + aoff];
    const bf16x8 b0 = *(const bf16x8*)&lw[(qc     ) * KC + aoff];
    const bf16x8 b1 = *(const bf16x8*)&lw[(qc + 16) * KC + aoff];
    acc00 = __builtin_amdgcn_mfma_f32_16x16x32_bf16(a0, b0, acc00, 0, 0, 0);
    acc01 = __builtin_amdgcn_mfma_f32_16x16x32_bf16(a0, b1, acc01, 0, 0, 0);
    acc10 = __builtin_amdgcn_mfma_f32_16x16x32_bf16(a1, b0, acc10, 0, 0, 0);
    acc11 = __builtin_amdgcn_mfma_f32_16x16x32_bf16(a1, b1, acc11, 0, 0, 0);
    __syncthreads();                                   // drains vmcnt (next buf ready) + lgkm
  }

  // C/D layout (m89-verified): col = lane&15, row = (lane>>4)*4 + j
  const int orow  = r0 + qr + (lane >> 4) * 4;
  const int ocol0 = c0 + qc + (lane & 15);
#pragma unroll
  for (int j = 0; j < 4; ++j) {
    unsafeAtomicAdd(&out[(size_t)(orow + j)      * OUT_DIM + ocol0     ], acc00[j]);
    unsafeAtomicAdd(&out[(size_t)(orow + j)      * OUT_DIM + ocol0 + 16], acc01[j]);
    unsafeAtomicAdd(&out[(size_t)(orow + 16 + j) * OUT_DIM + ocol0     ], acc10[j]);
    unsafeAtomicAdd(&out[(size_t)(orow + 16 + j) * OUT_DIM + ocol0 + 16], acc11[j]);
  }
}

extern "C" void kernel_launch(void* const* d_in, const int* in_sizes, int n_in,
                              void* d_out, int out_size, void* d_ws, size_t ws_size,
                              hipStream_t stream) {
  const float* x    = (const float*)d_in[0];
  const float* grid = (const float*)d_in[1];
  const float* coef = (const float*)d_in[2];
  const float* sb   = (const float*)d_in[3];
  const float* ss   = (const float*)d_in[4];
  const float* mask = (const float*)d_in[5];
  float* out = (float*)d_out;

  unsigned short* Abuf = (unsigned short*)d_ws;                    // 512*6144 bf16 = 6 MiB
  unsigned short* Wbuf = Abuf + (size_t)BATCH * KTOT;              // 512*6144 bf16 = 6 MiB

  hipMemsetAsync(d_out, 0, (size_t)out_size * sizeof(float), stream);
  build_A<<<dim3(BATCH * IN_DIM / 256), 256, 0, stream>>>(x, grid, Abuf);
  build_W<<<dim3(IN_DIM * OUT_DIM / 256), 256, 0, stream>>>(coef, sb, ss, mask, Wbuf);
  gemm_kan<<<dim3(64, SPLITK), 256, 0, stream>>>(Abuf, Wbuf, out);
}

// Round 2
// 36.837 us; speedup vs baseline: 1.2739x; 1.2739x over previous
//
#include <hip/hip_runtime.h>
#include <cstdint>

#define IN_DIM  512
#define OUT_DIM 512
#define BATCH   512
#define KPI     12                 // 11 basis + 1 silu slot per input dim
#define KTOT    (IN_DIM * KPI)     // 6144
#define TILE    64
#define KC      32
#define SPLITK  8
#define KCHUNK  (KTOT / SPLITK)    // 768
#define NSTEP   (KCHUNK / KC)      // 24

typedef __attribute__((ext_vector_type(8))) short bf16x8;
typedef __attribute__((ext_vector_type(4))) float f32x4;

static __device__ __forceinline__ unsigned short f2bf(float f) {
  union { float f; unsigned int u; } v; v.f = f;
  return (unsigned short)((v.u + 0x7FFFu + ((v.u >> 16) & 1u)) >> 16);  // RNE
}

// Fused builder: blocks [0,1024) build A (and zero d_out), blocks [1024,2048) build Wt.
// A[b][i*12 + k] : k=0..10 spline basis of x[b,i], k=11 silu(x[b,i]).  bf16, K-minor.
// Wt[o][i*12 + k] = mask*scale_sp*coef[i,o,k] (k<11), mask*scale_base[i,o] (k=11). bf16, K-minor.
__global__ __launch_bounds__(256) void build_AW(const float* __restrict__ x,
                                                const float* __restrict__ grid,
                                                const float* __restrict__ coef,
                                                const float* __restrict__ sb,
                                                const float* __restrict__ ss,
                                                const float* __restrict__ mask,
                                                unsigned short* __restrict__ A,
                                                unsigned short* __restrict__ Wt,
                                                float* __restrict__ out) {
  const int bid = blockIdx.x;
  if (bid < 1024) {
    const int idx = bid * 256 + threadIdx.x;           // idx = b*512 + i  (262144 total == out_size)
    out[idx] = 0.0f;                                   // zero d_out for the gemm's atomic epilogue
    const int i = idx & (IN_DIM - 1);
    const float xv = x[idx];
    float g[15];
#pragma unroll
    for (int t = 0; t < 15; ++t) g[t] = grid[i * 15 + t];
    float B[14];
#pragma unroll
    for (int t = 0; t < 14; ++t) B[t] = (xv >= g[t] && xv < g[t + 1]) ? 1.0f : 0.0f;
#pragma unroll
    for (int j = 1; j <= 3; ++j) {
#pragma unroll
      for (int t = 0; t + j < 14; ++t) {
        const float left  = (xv - g[t]) / (g[t + j] - g[t]);
        const float right = (g[t + j + 1] - xv) / (g[t + j + 1] - g[t + 1]);
        B[t] = left * B[t] + right * B[t + 1];
      }
    }
    const float silu = xv / (1.0f + __expf(-xv));
    unsigned short* dst = A + (size_t)idx * KPI;       // == A[b*6144 + i*12]
    const ushort4 p0 = make_ushort4(f2bf(B[0]), f2bf(B[1]), f2bf(B[2]),  f2bf(B[3]));
    const ushort4 p1 = make_ushort4(f2bf(B[4]), f2bf(B[5]), f2bf(B[6]),  f2bf(B[7]));
    const ushort4 p2 = make_ushort4(f2bf(B[8]), f2bf(B[9]), f2bf(B[10]), f2bf(silu));
    ((ushort4*)dst)[0] = p0; ((ushort4*)dst)[1] = p1; ((ushort4*)dst)[2] = p2;
  } else {
    const int idx = (bid - 1024) * 256 + threadIdx.x;
    const int o = idx & (OUT_DIM - 1);
    const int i = idx >> 9;
    const int io = i * OUT_DIM + o;
    const float m   = mask[io];
    const float scs = m * ss[io];
    const float scb = m * sb[io];
    const float* cp = coef + (size_t)io * 11;
    float c[11];
#pragma unroll
    for (int k = 0; k < 11; ++k) c[k] = scs * cp[k];
    unsigned short* dst = Wt + (size_t)o * KTOT + i * KPI;
    const ushort4 p0 = make_ushort4(f2bf(c[0]), f2bf(c[1]), f2bf(c[2]),  f2bf(c[3]));
    const ushort4 p1 = make_ushort4(f2bf(c[4]), f2bf(c[5]), f2bf(c[6]),  f2bf(c[7]));
    const ushort4 p2 = make_ushort4(f2bf(c[8]), f2bf(c[9]), f2bf(c[10]), f2bf(scb));
    ((ushort4*)dst)[0] = p0; ((ushort4*)dst)[1] = p1; ((ushort4*)dst)[2] = p2;
  }
}

// out(512x512,f32) += A(512x6144,bf16) @ Wt^T(6144x512,bf16).  64x64 tile, split-K=8, atomic epilogue.
__global__ __launch_bounds__(256) void gemm_kan(const unsigned short* __restrict__ A,
                                                const unsigned short* __restrict__ Wt,
                                                float* __restrict__ out) {
  __shared__ unsigned short lds[2][2][TILE * KC];      // [buf][0=A,1=W][64*32] = 16 KiB
  const int tid  = threadIdx.x;
  const int lane = tid & 63;
  const int wq   = tid >> 6;                           // wave 0..3
  const int r0   = (blockIdx.x & 7) * TILE;
  const int c0   = (blockIdx.x >> 3) * TILE;
  const int kk0  = blockIdx.y * KCHUNK;

  // staging: thread t loads 16B of row (t>>2), k-slot (t&3); LDS dest = wave-uniform base + lane*16
  const unsigned short* ga = A  + (size_t)(r0 + (tid >> 2)) * KTOT + kk0 + (tid & 3) * 8;
  const unsigned short* gw = Wt + (size_t)(c0 + (tid >> 2)) * KTOT + kk0 + (tid & 3) * 8;

  const int qr = (wq >> 1) * 32;                       // wave's 32x32 quadrant
  const int qc = (wq & 1) * 32;

  f32x4 acc00 = {0.f, 0.f, 0.f, 0.f};
  f32x4 acc01 = acc00, acc10 = acc00, acc11 = acc00;

  __builtin_amdgcn_global_load_lds((const __attribute__((address_space(1))) void*)ga,
                                   (__attribute__((address_space(3))) void*)&lds[0][0][wq * 512], 16, 0, 0);
  __builtin_amdgcn_global_load_lds((const __attribute__((address_space(1))) void*)gw,
                                   (__attribute__((address_space(3))) void*)&lds[0][1][wq * 512], 16, 0, 0);
  __syncthreads();

  const int aoff = (lane & 15) * KC + (lane >> 4) * 8; // identical sigma for A-frag and B-frag
  for (int t = 0; t < NSTEP; ++t) {
    const int buf = t & 1;
    if (t + 1 < NSTEP) {
      __builtin_amdgcn_global_load_lds((const __attribute__((address_space(1))) void*)(ga + (t + 1) * KC),
                                       (__attribute__((address_space(3))) void*)&lds[buf ^ 1][0][wq * 512], 16, 0, 0);
      __builtin_amdgcn_global_load_lds((const __attribute__((address_space(1))) void*)(gw + (t + 1) * KC),
                                       (__attribute__((address_space(3))) void*)&lds[buf ^ 1][1][wq * 512], 16, 0, 0);
    }
    const unsigned short* la = &lds[buf][0][0];
    const unsigned short* lw = &lds[buf][1][0];
    const bf16x8 a0 = *(const bf16x8*)&la[(qr     ) * KC + aoff];
    const bf16x8 a1 = *(const bf16x8*)&la[(qr + 16) * KC + aoff];
    const bf16x8 b0 = *(const bf16x8*)&lw[(qc     ) * KC + aoff];
    const bf16x8 b1 = *(const bf16x8*)&lw[(qc + 16) * KC + aoff];
    acc00 = __builtin_amdgcn_mfma_f32_16x16x32_bf16(a0, b0, acc00, 0, 0, 0);
    acc01 = __builtin_amdgcn_mfma_f32_16x16x32_bf16(a0, b1, acc01, 0, 0, 0);
    acc10 = __builtin_amdgcn_mfma_f32_16x16x32_bf16(a1, b0, acc10, 0, 0, 0);
    acc11 = __builtin_amdgcn_mfma_f32_16x16x32_bf16(a1, b1, acc11, 0, 0, 0);
    __syncthreads();                                   // drains vmcnt (next buf ready) + lgkm
  }

  // C/D layout (m89-verified): col = lane&15, row = (lane>>4)*4 + j
  const int orow  = r0 + qr + (lane >> 4) * 4;
  const int ocol0 = c0 + qc + (lane & 15);
#pragma unroll
  for (int j = 0; j < 4; ++j) {
    unsafeAtomicAdd(&out[(size_t)(orow + j)      * OUT_DIM + ocol0     ], acc00[j]);
    unsafeAtomicAdd(&out[(size_t)(orow + j)      * OUT_DIM + ocol0 + 16], acc01[j]);
    unsafeAtomicAdd(&out[(size_t)(orow + 16 + j) * OUT_DIM + ocol0     ], acc10[j]);
    unsafeAtomicAdd(&out[(size_t)(orow + 16 + j) * OUT_DIM + ocol0 + 16], acc11[j]);
  }
}

extern "C" void kernel_launch(void* const* d_in, const int* in_sizes, int n_in,
                              void* d_out, int out_size, void* d_ws, size_t ws_size,
                              hipStream_t stream) {
  const float* x    = (const float*)d_in[0];
  const float* grid = (const float*)d_in[1];
  const float* coef = (const float*)d_in[2];
  const float* sb   = (const float*)d_in[3];
  const float* ss   = (const float*)d_in[4];
  const float* mask = (const float*)d_in[5];
  float* out = (float*)d_out;

  unsigned short* Abuf = (unsigned short*)d_ws;                    // 512*6144 bf16 = 6 MiB
  unsigned short* Wbuf = Abuf + (size_t)BATCH * KTOT;              // 512*6144 bf16 = 6 MiB

  build_AW<<<dim3(2048), 256, 0, stream>>>(x, grid, coef, sb, ss, mask, Abuf, Wbuf, out);
  gemm_kan<<<dim3(64, SPLITK), 256, 0, stream>>>(Abuf, Wbuf, out);
}

// Round 3
// 35.689 us; speedup vs baseline: 1.3149x; 1.0322x over previous
//
#include <hip/hip_runtime.h>
#include <cstdint>

#define IN_DIM  512
#define OUT_DIM 512
#define BATCH   512
#define KPI     12                 // 11 basis + 1 silu slot per input dim
#define KTOT    (IN_DIM * KPI)     // 6144
#define TILE    64
#define KC      32
#define SPLITK  8
#define KCHUNK  (KTOT / SPLITK)    // 768
#define NSTEP   (KCHUNK / KC)      // 24
#define OUT_ELEMS (BATCH * OUT_DIM)

typedef __attribute__((ext_vector_type(8))) short bf16x8;
typedef __attribute__((ext_vector_type(4))) float f32x4;

static __device__ __forceinline__ unsigned short f2bf(float f) {
  union { float f; unsigned int u; } v; v.f = f;
  return (unsigned short)((v.u + 0x7FFFu + ((v.u >> 16) & 1u)) >> 16);  // RNE
}

// Fused builder: blocks [0,1024) build A, blocks [1024,2048) build Wt.
// A[b][i*12 + k] : k=0..10 spline basis of x[b,i], k=11 silu(x[b,i]).  bf16, K-minor.
// Wt[o][i*12 + k] = mask*scale_sp*coef[i,o,k] (k<11), mask*scale_base[i,o] (k=11). bf16, K-minor.
__global__ __launch_bounds__(256) void build_AW(const float* __restrict__ x,
                                                const float* __restrict__ grid,
                                                const float* __restrict__ coef,
                                                const float* __restrict__ sb,
                                                const float* __restrict__ ss,
                                                const float* __restrict__ mask,
                                                unsigned short* __restrict__ A,
                                                unsigned short* __restrict__ Wt) {
  const int bid = blockIdx.x;
  if (bid < 1024) {
    const int idx = bid * 256 + threadIdx.x;           // idx = b*512 + i
    const int i = idx & (IN_DIM - 1);
    const float xv = x[idx];
    float g[15];
#pragma unroll
    for (int t = 0; t < 15; ++t) g[t] = grid[i * 15 + t];
    float B[14];
#pragma unroll
    for (int t = 0; t < 14; ++t) B[t] = (xv >= g[t] && xv < g[t + 1]) ? 1.0f : 0.0f;
#pragma unroll
    for (int j = 1; j <= 3; ++j) {
#pragma unroll
      for (int t = 0; t + j < 14; ++t) {
        const float left  = (xv - g[t]) / (g[t + j] - g[t]);
        const float right = (g[t + j + 1] - xv) / (g[t + j + 1] - g[t + 1]);
        B[t] = left * B[t] + right * B[t + 1];
      }
    }
    const float silu = xv / (1.0f + __expf(-xv));
    unsigned short* dst = A + (size_t)idx * KPI;
    const ushort4 p0 = make_ushort4(f2bf(B[0]), f2bf(B[1]), f2bf(B[2]),  f2bf(B[3]));
    const ushort4 p1 = make_ushort4(f2bf(B[4]), f2bf(B[5]), f2bf(B[6]),  f2bf(B[7]));
    const ushort4 p2 = make_ushort4(f2bf(B[8]), f2bf(B[9]), f2bf(B[10]), f2bf(silu));
    ((ushort4*)dst)[0] = p0; ((ushort4*)dst)[1] = p1; ((ushort4*)dst)[2] = p2;
  } else {
    const int idx = (bid - 1024) * 256 + threadIdx.x;
    const int o = idx & (OUT_DIM - 1);
    const int i = idx >> 9;
    const int io = i * OUT_DIM + o;
    const float m   = mask[io];
    const float scs = m * ss[io];
    const float scb = m * sb[io];
    const float* cp = coef + (size_t)io * 11;
    float c[11];
#pragma unroll
    for (int k = 0; k < 11; ++k) c[k] = scs * cp[k];
    unsigned short* dst = Wt + (size_t)o * KTOT + i * KPI;
    const ushort4 p0 = make_ushort4(f2bf(c[0]), f2bf(c[1]), f2bf(c[2]),  f2bf(c[3]));
    const ushort4 p1 = make_ushort4(f2bf(c[4]), f2bf(c[5]), f2bf(c[6]),  f2bf(c[7]));
    const ushort4 p2 = make_ushort4(f2bf(c[8]), f2bf(c[9]), f2bf(c[10]), f2bf(scb));
    ((ushort4*)dst)[0] = p0; ((ushort4*)dst)[1] = p1; ((ushort4*)dst)[2] = p2;
  }
}

// part[s](512x512,f32) = A(512x6144,bf16) @ Wt^T slice.  64x64 tile, split-K=8, plain stores.
__global__ __launch_bounds__(256) void gemm_kan(const unsigned short* __restrict__ A,
                                                const unsigned short* __restrict__ Wt,
                                                float* __restrict__ part) {
  __shared__ unsigned short lds[2][2][TILE * KC];      // [buf][0=A,1=W][64*32] = 16 KiB
  const int tid  = threadIdx.x;
  const int lane = tid & 63;
  const int wq   = tid >> 6;                           // wave 0..3
  const int r0   = (blockIdx.x & 7) * TILE;
  const int c0   = (blockIdx.x >> 3) * TILE;
  const int kk0  = blockIdx.y * KCHUNK;

  const unsigned short* ga = A  + (size_t)(r0 + (tid >> 2)) * KTOT + kk0 + (tid & 3) * 8;
  const unsigned short* gw = Wt + (size_t)(c0 + (tid >> 2)) * KTOT + kk0 + (tid & 3) * 8;

  const int qr = (wq >> 1) * 32;                       // wave's 32x32 quadrant
  const int qc = (wq & 1) * 32;

  f32x4 acc00 = {0.f, 0.f, 0.f, 0.f};
  f32x4 acc01 = acc00, acc10 = acc00, acc11 = acc00;

  __builtin_amdgcn_global_load_lds((const __attribute__((address_space(1))) void*)ga,
                                   (__attribute__((address_space(3))) void*)&lds[0][0][wq * 512], 16, 0, 0);
  __builtin_amdgcn_global_load_lds((const __attribute__((address_space(1))) void*)gw,
                                   (__attribute__((address_space(3))) void*)&lds[0][1][wq * 512], 16, 0, 0);
  __syncthreads();

  const int aoff = (lane & 15) * KC + (lane >> 4) * 8; // identical sigma for A-frag and B-frag
  for (int t = 0; t < NSTEP; ++t) {
    const int buf = t & 1;
    if (t + 1 < NSTEP) {
      __builtin_amdgcn_global_load_lds((const __attribute__((address_space(1))) void*)(ga + (t + 1) * KC),
                                       (__attribute__((address_space(3))) void*)&lds[buf ^ 1][0][wq * 512], 16, 0, 0);
      __builtin_amdgcn_global_load_lds((const __attribute__((address_space(1))) void*)(gw + (t + 1) * KC),
                                       (__attribute__((address_space(3))) void*)&lds[buf ^ 1][1][wq * 512], 16, 0, 0);
    }
    const unsigned short* la = &lds[buf][0][0];
    const unsigned short* lw = &lds[buf][1][0];
    const bf16x8 a0 = *(const bf16x8*)&la[(qr     ) * KC + aoff];
    const bf16x8 a1 = *(const bf16x8*)&la[(qr + 16) * KC + aoff];
    const bf16x8 b0 = *(const bf16x8*)&lw[(qc     ) * KC + aoff];
    const bf16x8 b1 = *(const bf16x8*)&lw[(qc + 16) * KC + aoff];
    acc00 = __builtin_amdgcn_mfma_f32_16x16x32_bf16(a0, b0, acc00, 0, 0, 0);
    acc01 = __builtin_amdgcn_mfma_f32_16x16x32_bf16(a0, b1, acc01, 0, 0, 0);
    acc10 = __builtin_amdgcn_mfma_f32_16x16x32_bf16(a1, b0, acc10, 0, 0, 0);
    acc11 = __builtin_amdgcn_mfma_f32_16x16x32_bf16(a1, b1, acc11, 0, 0, 0);
    __syncthreads();
  }

  // C/D layout (m89-verified): col = lane&15, row = (lane>>4)*4 + j
  float* pb = part + (size_t)blockIdx.y * OUT_ELEMS;
  const int orow  = r0 + qr + (lane >> 4) * 4;
  const int ocol0 = c0 + qc + (lane & 15);
#pragma unroll
  for (int j = 0; j < 4; ++j) {
    pb[(size_t)(orow + j)      * OUT_DIM + ocol0     ] = acc00[j];
    pb[(size_t)(orow + j)      * OUT_DIM + ocol0 + 16] = acc01[j];
    pb[(size_t)(orow + 16 + j) * OUT_DIM + ocol0     ] = acc10[j];
    pb[(size_t)(orow + 16 + j) * OUT_DIM + ocol0 + 16] = acc11[j];
  }
}

// out = sum over 8 split-K partials, float4-vectorized.
__global__ __launch_bounds__(256) void reduce_k(const float* __restrict__ part,
                                                float* __restrict__ out) {
  const int idx = (blockIdx.x * 256 + threadIdx.x) * 4;
  f32x4 s = *(const f32x4*)&part[idx];
#pragma unroll
  for (int p = 1; p < SPLITK; ++p) s += *(const f32x4*)&part[(size_t)p * OUT_ELEMS + idx];
  *(f32x4*)&out[idx] = s;
}

extern "C" void kernel_launch(void* const* d_in, const int* in_sizes, int n_in,
                              void* d_out, int out_size, void* d_ws, size_t ws_size,
                              hipStream_t stream) {
  const float* x    = (const float*)d_in[0];
  const float* grid = (const float*)d_in[1];
  const float* coef = (const float*)d_in[2];
  const float* sb   = (const float*)d_in[3];
  const float* ss   = (const float*)d_in[4];
  const float* mask = (const float*)d_in[5];
  float* out = (float*)d_out;

  unsigned short* Abuf = (unsigned short*)d_ws;                    // 6 MiB
  unsigned short* Wbuf = Abuf + (size_t)BATCH * KTOT;              // 6 MiB
  float* part = (float*)(Wbuf + (size_t)OUT_DIM * KTOT);           // 8 x 1 MiB partials

  build_AW<<<dim3(2048), 256, 0, stream>>>(x, grid, coef, sb, ss, mask, Abuf, Wbuf);
  gemm_kan<<<dim3(64, SPLITK), 256, 0, stream>>>(Abuf, Wbuf, part);
  reduce_k<<<dim3(OUT_ELEMS / 4 / 256), 256, 0, stream>>>(part, out);
}